// Round 3
// baseline (92.700 us; speedup 1.0000x reference)
//
#include <hip/hip_runtime.h>
#include <hip/hip_bf16.h>

#define B_ 2
#define S_ 1024
#define E_ 128
#define H_ 4
#define D_ 32
#define BHSD (B_ * H_ * S_ * D_)   // 262144 floats per tensor

// ---------------------------------------------------------------------------
// Kernel A: fused QKV projection.
//   q/k/v[e] = sum_c x[row][c] * W[e][c] + b[e], written in (B,H,S,D) layout.
// grid = (row_tiles=256, mat=3), block = 128 threads (thread = output col e).
// ---------------------------------------------------------------------------
__global__ __launch_bounds__(128) void qkv_kernel(
    const float* __restrict__ x,
    const float* __restrict__ Wq, const float* __restrict__ bq,
    const float* __restrict__ Wk, const float* __restrict__ bk,
    const float* __restrict__ Wv, const float* __restrict__ bv,
    float* __restrict__ ws) {
  const int mat = blockIdx.y;
  const float* W    = (mat == 0) ? Wq : (mat == 1) ? Wk : Wv;
  const float* bias = (mat == 0) ? bq : (mat == 1) ? bk : bv;
  float* outbase = ws + (size_t)mat * BHSD;

  const int row0 = blockIdx.x * 8;
  const int t = threadIdx.x;

  __shared__ __align__(16) float xs[8 * E_];
  const float4* xg = (const float4*)(x + (size_t)row0 * E_);
  float4* xs4 = (float4*)xs;
  #pragma unroll
  for (int i = 0; i < 2; ++i) xs4[t + i * 128] = xg[t + i * 128];
  __syncthreads();

  const int col = t;                       // output feature e in [0,128)
  const float4* W4 = (const float4*)(W + (size_t)col * E_);

  float acc[8];
  #pragma unroll
  for (int r = 0; r < 8; ++r) acc[r] = 0.f;

  #pragma unroll 4
  for (int c4 = 0; c4 < E_ / 4; ++c4) {
    float4 w = W4[c4];
    #pragma unroll
    for (int r = 0; r < 8; ++r) {
      float4 xv = xs4[r * (E_ / 4) + c4];
      acc[r] += xv.x * w.x + xv.y * w.y + xv.z * w.z + xv.w * w.w;
    }
  }

  const float bcol = bias[col];
  const int h = col >> 5, d = col & 31;
  #pragma unroll
  for (int r = 0; r < 8; ++r) {
    int row = row0 + r;                    // flat row over B*S
    int b = row >> 10, s = row & 1023;
    outbase[(((size_t)(b * H_ + h)) * S_ + s) * D_ + d] = acc[r] + bcol;
  }
}

// ---------------------------------------------------------------------------
// Kernel B: ultrametric attention partials, lane-per-Q-row, no LDS in hot loop.
//   Each lane holds one full Q row (32 f32) + accumulator o[32]; the wave
//   walks keys with wave-uniform K/V row loads (L1/L2-resident, broadcast).
//   dist >= 0 so p = exp(-dist) needs NO online-softmax rescaling in fp32.
// grid.x = 128 row-tiles * 4 key-chunks = 512 blocks, 256 threads.
// Waves 0..3 of a block process the same 64 rows over different 64-key
// sub-chunks (this block's 256-key chunk); the 4 waves are merged in LDS and
// the block writes ONE raw partial (o,l) per row to workspace. Cross-block
// (kc) merge happens in out_kernel.
// ---------------------------------------------------------------------------
__global__ __launch_bounds__(256) void attn_kernel(
    const float* __restrict__ qg, const float* __restrict__ kg,
    const float* __restrict__ vg,
    float* __restrict__ part_o, float* __restrict__ part_l) {
  const int rt = blockIdx.x >> 2;      // row tile 0..127
  const int kc = blockIdx.x & 3;       // key chunk 0..3
  const int t = threadIdx.x;
  const int w = t >> 6;                // wave 0..3
  const int lane = t & 63;
  const int bh = rt >> 4;              // head index (b*H + h), uniform per block
  const int srow = (rt & 15) * 64 + lane;   // s of my Q row

  // Q row -> registers
  const float* qrow = qg + ((size_t)bh * S_ + srow) * D_;
  float q[32];
  #pragma unroll
  for (int i = 0; i < 8; ++i) {
    float4 v4 = *(const float4*)(qrow + i * 4);
    q[i * 4 + 0] = v4.x; q[i * 4 + 1] = v4.y;
    q[i * 4 + 2] = v4.z; q[i * 4 + 3] = v4.w;
  }

  float o[32];
  #pragma unroll
  for (int i = 0; i < 32; ++i) o[i] = 0.f;
  float l = 0.f;

  const float* kbase = kg + (size_t)bh * S_ * D_;
  const float* vbase = vg + (size_t)bh * S_ * D_;
  const int j0 = kc * 256 + w * 64;    // this wave's 64-key sub-chunk

  #pragma unroll 2
  for (int j = j0; j < j0 + 64; ++j) {
    const float* kr = kbase + (size_t)j * D_;  // wave-uniform address
    const float* vr = vbase + (size_t)j * D_;

    float kv[32];
    #pragma unroll
    for (int i = 0; i < 8; ++i) {
      float4 v4 = *(const float4*)(kr + i * 4);
      kv[i * 4 + 0] = v4.x; kv[i * 4 + 1] = v4.y;
      kv[i * 4 + 2] = v4.z; kv[i * 4 + 3] = v4.w;
    }

    // Chebyshev distance: 4 independent max3 chains (abs folds into operands)
    float c0 = 0.f, c1 = 0.f, c2 = 0.f, c3 = 0.f;
    #pragma unroll
    for (int i = 0; i < 4; ++i) {
      c0 = fmaxf(c0, fmaxf(fabsf(q[i*8+0] - kv[i*8+0]), fabsf(q[i*8+1] - kv[i*8+1])));
      c1 = fmaxf(c1, fmaxf(fabsf(q[i*8+2] - kv[i*8+2]), fabsf(q[i*8+3] - kv[i*8+3])));
      c2 = fmaxf(c2, fmaxf(fabsf(q[i*8+4] - kv[i*8+4]), fabsf(q[i*8+5] - kv[i*8+5])));
      c3 = fmaxf(c3, fmaxf(fabsf(q[i*8+6] - kv[i*8+6]), fabsf(q[i*8+7] - kv[i*8+7])));
    }
    const float dist = fmaxf(fmaxf(c0, c1), fmaxf(c2, c3));
    const float p = __expf(-dist);
    l += p;

    // O += p * V[j]
    #pragma unroll
    for (int i = 0; i < 8; ++i) {
      float4 v4 = *(const float4*)(vr + i * 4);
      o[i * 4 + 0] = fmaf(p, v4.x, o[i * 4 + 0]);
      o[i * 4 + 1] = fmaf(p, v4.y, o[i * 4 + 1]);
      o[i * 4 + 2] = fmaf(p, v4.z, o[i * 4 + 2]);
      o[i * 4 + 3] = fmaf(p, v4.w, o[i * 4 + 3]);
    }
  }

  // ---- in-block merge across the 4 waves, write raw partial to ws ----
  __shared__ float sm_o[4][64][33];   // pad 33
  __shared__ float sm_l[4][64];
  #pragma unroll
  for (int e = 0; e < 32; ++e) sm_o[w][lane][e] = o[e];
  sm_l[w][lane] = l;
  __syncthreads();

  const int row = t >> 2;             // 0..63
  const int sl = t & 3;               // dim slice: sl*8 .. sl*8+7
  float r8[8];
  #pragma unroll
  for (int e = 0; e < 8; ++e) {
    const int d = sl * 8 + e;
    r8[e] = sm_o[0][row][d] + sm_o[1][row][d] +
            sm_o[2][row][d] + sm_o[3][row][d];
  }
  float* po = part_o + ((size_t)(rt * 4 + kc) * 64 + row) * 32 + sl * 8;
  *(float4*)(po + 0) = make_float4(r8[0], r8[1], r8[2], r8[3]);
  *(float4*)(po + 4) = make_float4(r8[4], r8[5], r8[6], r8[7]);
  if (sl == 0) {
    part_l[(size_t)(rt * 4 + kc) * 64 + row] =
        sm_l[0][row] + sm_l[1][row] + sm_l[2][row] + sm_l[3][row];
  }
}

// ---------------------------------------------------------------------------
// Kernel C: merge kc-partials -> att rows in LDS -> out = att @ Wo^T + bo
// grid = 256 blocks (8 flat rows each), block = 128.
// ---------------------------------------------------------------------------
__global__ __launch_bounds__(128) void out_kernel(
    const float* __restrict__ part_o, const float* __restrict__ part_l,
    const float* __restrict__ Wo, const float* __restrict__ bo,
    float* __restrict__ out) {
  const int row0 = blockIdx.x * 8;
  const int t = threadIdx.x;

  __shared__ __align__(16) float xs[8 * E_];

  // build merged attended rows into LDS: xs[i][e], e = h*32 + d
  const int e = t;
  const int h = e >> 5, d = e & 31;
  #pragma unroll
  for (int i = 0; i < 8; ++i) {
    const int r = row0 + i;
    const int b = r >> 10, s = r & 1023;
    const int rt = (b * H_ + h) * 16 + (s >> 6);
    const int lrow = s & 63;
    float acc = 0.f, lsum = 0.f;
    #pragma unroll
    for (int kc = 0; kc < 4; ++kc) {
      const size_t base = (size_t)(rt * 4 + kc) * 64 + lrow;
      acc  += part_o[base * 32 + d];
      lsum += part_l[base];
    }
    xs[i * E_ + e] = acc / lsum;
  }
  __syncthreads();

  const int col = t;
  const float4* W4 = (const float4*)(Wo + (size_t)col * E_);
  const float4* xs4 = (const float4*)xs;

  float acc[8];
  #pragma unroll
  for (int r = 0; r < 8; ++r) acc[r] = 0.f;

  #pragma unroll 4
  for (int c4 = 0; c4 < E_ / 4; ++c4) {
    float4 w = W4[c4];
    #pragma unroll
    for (int r = 0; r < 8; ++r) {
      float4 xv = xs4[r * (E_ / 4) + c4];
      acc[r] += xv.x * w.x + xv.y * w.y + xv.z * w.z + xv.w * w.w;
    }
  }

  const float bcol = bo[col];
  #pragma unroll
  for (int r = 0; r < 8; ++r)
    out[(size_t)(row0 + r) * E_ + col] = acc[r] + bcol;
}

// ---------------------------------------------------------------------------
extern "C" void kernel_launch(void* const* d_in, const int* in_sizes, int n_in,
                              void* d_out, int out_size, void* d_ws, size_t ws_size,
                              hipStream_t stream) {
  const float* x  = (const float*)d_in[0];
  const float* Wq = (const float*)d_in[1];
  const float* bq = (const float*)d_in[2];
  const float* Wk = (const float*)d_in[3];
  const float* bk = (const float*)d_in[4];
  const float* Wv = (const float*)d_in[5];
  const float* bv = (const float*)d_in[6];
  const float* Wo = (const float*)d_in[7];
  const float* bo = (const float*)d_in[8];
  float* ws  = (float*)d_ws;
  float* out = (float*)d_out;

  // ws layout (floats):
  //   [0, BHSD)        q
  //   [BHSD, 2*BHSD)   k
  //   [2*BHSD, 3*BHSD) v
  //   [3*BHSD, +1048576) part_o  : [128 rt][4 kc][64 row][32 d]
  //   then 32768         part_l  : [128 rt][4 kc][64 row]
  float* qd = ws;
  float* kd = ws + (size_t)BHSD;
  float* vd = ws + 2 * (size_t)BHSD;
  float* part_o = ws + 3 * (size_t)BHSD;
  float* part_l = part_o + (size_t)128 * 4 * 64 * 32;

  qkv_kernel<<<dim3((B_ * S_) / 8, 3), 128, 0, stream>>>(x, Wq, bq, Wk, bk, Wv, bv, ws);
  attn_kernel<<<dim3((B_ * H_ * S_ / 64) * 4), 256, 0, stream>>>(qd, kd, vd, part_o, part_l);
  out_kernel<<<dim3((B_ * S_) / 8), 128, 0, stream>>>(part_o, part_l, Wo, bo, out);
}